// Round 6
// baseline (314.209 us; speedup 1.0000x reference)
//
#include <hip/hip_runtime.h>
#include <stdint.h>

// Workspace layout (float offsets)
#define WS_M2 0          // 16384 floats  (512 x 32)
#define WS_N2 16384      // 2048  floats  (64 x 32)
#define WS_WT 18432      // 131072 floats (32 x 4096), W transposed: Wt[r*4096+o]
#define WS_Z  149504     // 32768 floats  (1024 x 32)

// Direct global->LDS async copy, 16 B per lane. LDS dest is wave-uniform base
// (HW appends lane*16); global src must include lane*4 floats.
#define GLOAD_LDS16(gsrc, ldst)                                         \
    __builtin_amdgcn_global_load_lds(                                   \
        (const __attribute__((address_space(1))) uint32_t*)(gsrc),      \
        (__attribute__((address_space(3))) uint32_t*)(ldst), 16, 0, 0)

#define FMA4(A, X, mm) do { (A).x += (X).x*(mm); (A).y += (X).y*(mm); \
                            (A).z += (X).z*(mm); (A).w += (X).w*(mm); } while (0)

// ---------------------------------------------------------------------------
// Kernel A: collapse TT factor chains into small dense matrices. (unchanged)
// ---------------------------------------------------------------------------
__global__ __launch_bounds__(256) void precompute_kernel(
    const float* __restrict__ f0, const float* __restrict__ f1,
    const float* __restrict__ f2, const float* __restrict__ f3,
    const float* __restrict__ f4, const float* __restrict__ g0,
    const float* __restrict__ g1, const float* __restrict__ g2,
    float* __restrict__ ws)
{
    __shared__ float sA[8192];
    const int t = threadIdx.x;
    const int blk = blockIdx.x;
    if (blk < 8) {
        for (int i = t; i < 2048; i += 256) {
            int a01 = i >> 5, r2 = i & 31;
            int a0 = a01 >> 3, a1 = a01 & 7;
            float s = 0.f;
            #pragma unroll
            for (int r1 = 0; r1 < 32; ++r1)
                s += f0[a0*32 + r1] * f1[r1*256 + a1*32 + r2];
            sA[i] = s;
        }
        __syncthreads();
        for (int i = t; i < 2048; i += 256) {
            int a012 = blk*64 + (i >> 5), r3 = i & 31;
            int a01 = a012 >> 3, a2 = a012 & 7;
            float s = 0.f;
            #pragma unroll
            for (int r2 = 0; r2 < 32; ++r2)
                s += sA[a01*32 + r2] * f2[r2*256 + a2*32 + r3];
            ws[WS_M2 + a012*32 + r3] = s;
        }
    } else if (blk == 8) {
        for (int i = t; i < 2048; i += 256) {
            int a34 = i >> 5, s2 = i & 31;
            int a3 = a34 >> 3, a4 = a34 & 7;
            float s = 0.f;
            #pragma unroll
            for (int s1 = 0; s1 < 32; ++s1)
                s += f3[a3*32 + s1] * f4[s1*256 + a4*32 + s2];
            ws[WS_N2 + i] = s;
        }
    } else {
        const int j = blk - 9;   // 0..31, o-slice
        for (int i = t; i < 8192; i += 256) {
            int o01 = i >> 5, q = i & 31;
            int o0 = o01 >> 4, o1 = o01 & 15;
            float s = 0.f;
            #pragma unroll
            for (int p = 0; p < 32; ++p)
                s += g0[o0*32 + p] * g1[p*512 + o1*32 + q];
            sA[i] = s;
        }
        __syncthreads();
        for (int i = t; i < 4096; i += 256) {
            int o = j*128 + (i >> 5);
            int r = i & 31;
            int o01 = o >> 4, o2 = o & 15;
            float s = 0.f;
            #pragma unroll
            for (int q = 0; q < 32; ++q)
                s += sA[o01*32 + q] * g2[q*512 + o2*32 + r];
            ws[WS_WT + r*4096 + o] = s;
        }
    }
}

// ---------------------------------------------------------------------------
// Kernel B v6: 1024 blocks x 256 threads (4 waves), 1 batch/block.
//   Phase 1 tiled GEMM, k-split across waves (wave w: k in [128w,128w+128)).
//   Thread (tm = lane&7, tr = lane>>3) owns an 8m x 4r tile:
//     acc = float4 accA[4], accB[4]  (32 regs, constant-indexed).
//   Per k: x = 2 per-lane global dwordx4 (8 distinct 32B segs/wave,
//   line-coalesced, L1 on re-read); M2 = 1 per-lane ds_read_b128
//   (8 distinct addrs -> conflict-free, 8-lane broadcast); 32 FMAs.
//   M2 staged in 16-k chunks (512 floats) into a WAVE-PRIVATE LDS double
//   buffer via global_load_lds: zero barriers in the k-loop, one
//   s_waitcnt vmcnt(0) per chunk (stage issued a full chunk earlier).
// LDS map, s[12416] = 48.5 KB -> 3 blocks/CU (12 waves):
//   [0..4096)      M2 chunk dbuf: wave w at w*1024, halves of 512
//                  (dead after k-loop -> N2 [0..2048), T5 [2048..3072),
//                   spart [3072..3584))
//   [4096..12416)  partials, v1 layout: w*2080 + r*65 + m
//                  (after reduce: final T3t in region 0 = [4096..6176))
// ---------------------------------------------------------------------------
__global__ __launch_bounds__(256, 3) void main_kernel(
    const float* __restrict__ x, const float* __restrict__ core,
    const float* __restrict__ ws, float* __restrict__ zout)
{
    __shared__ float s[12416];
    const int t = threadIdx.x;
    const int b = blockIdx.x;
    const int w    = __builtin_amdgcn_readfirstlane(t >> 6);  // wave 0..3
    const int lane = t & 63;
    const int tm = lane & 7;    // m-octet: m = tm*8 .. tm*8+7
    const int tr = lane >> 3;   // r-quad:  r = tr*4 .. tr*4+3

    const float* __restrict__ xq  = x + (size_t)b*32768 + w*8192 + tm*8;
    const float* __restrict__ m2g = ws + WS_M2 + w*4096;   // wave's k-quarter
    float* __restrict__ mbuf = s + w*1024;                 // wave-private dbuf

    // prologue: stage M2 chunk 0 (16k x 32r = 512 floats), wave-private
    GLOAD_LDS16(m2g + lane*4,       mbuf);
    GLOAD_LDS16(m2g + 256 + lane*4, mbuf + 256);
    asm volatile("s_waitcnt vmcnt(0)" ::: "memory");

    float4 accA[4], accB[4];
    #pragma unroll
    for (int rr = 0; rr < 4; ++rr) {
        accA[rr].x = accA[rr].y = accA[rr].z = accA[rr].w = 0.f;
        accB[rr].x = accB[rr].y = accB[rr].z = accB[rr].w = 0.f;
    }

    #pragma unroll 1
    for (int c = 0; c < 8; ++c) {
        if (c < 7) {   // stage chunk c+1 into the other half (wave-private)
            const float* sm = m2g + (c+1)*512 + lane*4;
            float* dm = mbuf + ((c+1)&1)*512;
            GLOAD_LDS16(sm,       dm);
            GLOAD_LDS16(sm + 256, dm + 256);
        }
        const float* __restrict__ xc = xq + c*1024;              // c*16*64
        const float* __restrict__ mc = mbuf + (c&1)*512 + tr*4;
        #pragma unroll 2
        for (int kk = 0; kk < 16; ++kk) {
            float4 xlo = *(const float4*)(xc + kk*64);
            float4 xhi = *(const float4*)(xc + kk*64 + 4);
            float4 m4  = *(const float4*)(mc + kk*32);
            FMA4(accA[0], xlo, m4.x); FMA4(accB[0], xhi, m4.x);
            FMA4(accA[1], xlo, m4.y); FMA4(accB[1], xhi, m4.y);
            FMA4(accA[2], xlo, m4.z); FMA4(accB[2], xhi, m4.z);
            FMA4(accA[3], xlo, m4.w); FMA4(accB[3], xhi, m4.w);
        }
        // stage of c+1 (issued ~16k FMAs ago) must land before next compute;
        // x loads are already drained by their consuming FMAs -> ~free wait
        asm volatile("s_waitcnt vmcnt(0)" ::: "memory");
    }

    // ---- write per-wave partials, v1 pitch-65 layout (one-time cost)
    {
        float* pw = s + 4096 + w*2080;
        #pragma unroll
        for (int rr = 0; rr < 4; ++rr) {
            const int r = tr*4 + rr;
            float* d = pw + r*65 + tm*8;
            d[0]=accA[rr].x; d[1]=accA[rr].y; d[2]=accA[rr].z; d[3]=accA[rr].w;
            d[4]=accB[rr].x; d[5]=accB[rr].y; d[6]=accB[rr].z; d[7]=accB[rr].w;
        }
    }
    __syncthreads();

    // ---- stage N2 into [0..2048) (M2 dbuf dead) + reduce partials (disjoint)
    {
        const float4* n24 = (const float4*)(ws + WS_N2);
        float4* d = (float4*)s;
        d[t]       = n24[t];
        d[256 + t] = n24[256 + t];
    }
    {
        float* P = s + 4096;
        const int rr  = t >> 3;        // 0..31
        const int mb2 = (t & 7) * 8;   // 0,8,...,56
        float sum[8];
        #pragma unroll
        for (int i = 0; i < 8; ++i) {
            sum[i] = P[rr*65 + mb2 + i] + P[2080 + rr*65 + mb2 + i]
                   + P[4160 + rr*65 + mb2 + i] + P[6240 + rr*65 + mb2 + i];
        }
        // each thread writes only addresses it alone read -> no barrier needed
        #pragma unroll
        for (int i = 0; i < 8; ++i) P[rr*65 + mb2 + i] = sum[i];
    }
    __syncthreads();

    // ---- phase 3: T5[r3,s2] = sum_m T3t[r3,m] * N2[m,s2] -> [2048..3072)
    {
        const float* P = s + 4096;
        const int r3  = t >> 3;
        const int s2b = (t & 7) * 4;
        float a0=0.f, a1=0.f, a2=0.f, a3=0.f;
        #pragma unroll 8
        for (int m = 0; m < 64; ++m) {
            float av = P[r3*65 + m];
            const float* n = &s[m*32 + s2b];
            a0 += av*n[0]; a1 += av*n[1]; a2 += av*n[2]; a3 += av*n[3];
        }
        float* d = &s[2048 + r3*32 + s2b];
        d[0]=a0; d[1]=a1; d[2]=a2; d[3]=a3;
    }
    __syncthreads();

    // ---- phase 4: z[ro] = sum_k T5[k] * core[k,ro]
    {
        const int ro2 = t & 15;
        const int kc  = t >> 4;
        const float2* core2 = (const float2*)core;
        float s0 = 0.f, s1 = 0.f;
        const int k0 = kc * 64;
        for (int k = k0; k < k0 + 64; ++k) {
            float tv = s[2048 + k];
            float2 cv = core2[k*16 + ro2];
            s0 += tv*cv.x; s1 += tv*cv.y;
        }
        s[3072 + kc*32 + ro2*2 + 0] = s0;
        s[3072 + kc*32 + ro2*2 + 1] = s1;
    }
    __syncthreads();
    if (t < 32) {
        float acc = 0.f;
        #pragma unroll
        for (int kc = 0; kc < 16; ++kc) acc += s[3072 + kc*32 + t];
        zout[b*32 + t] = acc;
    }
}

// ---------------------------------------------------------------------------
// Kernel C: out[b,o] = sum_r z[b,r]*Wt[r,o] + bias[o]  (unchanged)
// ---------------------------------------------------------------------------
__global__ __launch_bounds__(256) void out_kernel(
    const float* __restrict__ ws, const float* __restrict__ bias,
    float* __restrict__ out)
{
    __shared__ float sW[8192];   // Wt tile [32][256]
    __shared__ float sZt[2176];  // z tile transposed [32 ro][68]
    __shared__ float sB[256];
    const int t  = threadIdx.x;
    const int bt = blockIdx.x;
    const int ot = blockIdx.y;

    {
        const float4* wt4 = (const float4*)(ws + WS_WT);
        float4* d = (float4*)sW;
        #pragma unroll
        for (int i = 0; i < 8; ++i) {
            int idx = i*256 + t;
            int ro = idx >> 6, oc = idx & 63;
            d[idx] = wt4[ro*1024 + ot*64 + oc];
        }
    }
    {
        const float4* z4 = (const float4*)(ws + WS_Z) + bt*512;
        #pragma unroll
        for (int i = 0; i < 2; ++i) {
            int idx = i*256 + t;
            int bl = idx >> 3, r4 = idx & 7;
            float4 v = z4[idx];
            sZt[(r4*4 + 0)*68 + bl] = v.x;
            sZt[(r4*4 + 1)*68 + bl] = v.y;
            sZt[(r4*4 + 2)*68 + bl] = v.z;
            sZt[(r4*4 + 3)*68 + bl] = v.w;
        }
    }
    if (t < 64) {
        const float4* b4 = (const float4*)bias + ot*64;
        ((float4*)sB)[t] = b4[t];
    }
    __syncthreads();

    const int oc = t & 63;
    const int bg = t >> 6;
    const float4* sW4 = (const float4*)sW;
    const float4 bv = ((const float4*)sB)[oc];
    float4* out4 = (float4*)out;

    for (int bi = 0; bi < 16; bi += 4) {
        const int bl = bg*16 + bi;
        float4 a0 = bv, a1 = bv, a2 = bv, a3 = bv;
        #pragma unroll
        for (int ro = 0; ro < 32; ++ro) {
            float4 w = sW4[ro*64 + oc];
            float4 z = *(const float4*)&sZt[ro*68 + bl];
            a0.x += z.x*w.x; a0.y += z.x*w.y; a0.z += z.x*w.z; a0.w += z.x*w.w;
            a1.x += z.y*w.x; a1.y += z.y*w.y; a1.z += z.y*w.z; a1.w += z.y*w.w;
            a2.x += z.z*w.x; a2.y += z.z*w.y; a2.z += z.z*w.z; a2.w += z.z*w.w;
            a3.x += z.w*w.x; a3.y += z.w*w.y; a3.z += z.w*w.z; a3.w += z.w*w.w;
        }
        const size_t obase = (size_t)(bt*64 + bl) * 1024 + ot*64 + oc;
        out4[obase + 0*1024] = a0;
        out4[obase + 1*1024] = a1;
        out4[obase + 2*1024] = a2;
        out4[obase + 3*1024] = a3;
    }
}

extern "C" void kernel_launch(void* const* d_in, const int* in_sizes, int n_in,
                              void* d_out, int out_size, void* d_ws, size_t ws_size,
                              hipStream_t stream)
{
    const float* x    = (const float*)d_in[0];
    const float* f0   = (const float*)d_in[1];
    const float* f1   = (const float*)d_in[2];
    const float* f2   = (const float*)d_in[3];
    const float* f3   = (const float*)d_in[4];
    const float* f4   = (const float*)d_in[5];
    const float* core = (const float*)d_in[6];
    const float* g0   = (const float*)d_in[7];
    const float* g1   = (const float*)d_in[8];
    const float* g2   = (const float*)d_in[9];
    const float* bias = (const float*)d_in[10];
    float* ws  = (float*)d_ws;
    float* out = (float*)d_out;

    precompute_kernel<<<41, 256, 0, stream>>>(f0, f1, f2, f3, f4, g0, g1, g2, ws);
    main_kernel<<<1024, 256, 0, stream>>>(x, core, ws, ws + WS_Z);
    out_kernel<<<dim3(16, 16), 256, 0, stream>>>(ws, bias, out);
}

// Round 7
// 265.153 us; speedup vs baseline: 1.1850x; 1.1850x over previous
//
#include <hip/hip_runtime.h>
#include <stdint.h>

// Workspace layout (float offsets)
#define WS_M2 0          // 16384 floats  (512 x 32)
#define WS_N2 16384      // 2048  floats  (64 x 32)
#define WS_WT 18432      // 131072 floats (32 x 4096), W transposed: Wt[r*4096+o]
#define WS_Z  149504     // 32768 floats  (1024 x 32)

// Direct global->LDS async copy, 16 B per lane. LDS dest is wave-uniform base
// (HW appends lane*16); global src must include lane*4 floats.
#define GLOAD_LDS16(gsrc, ldst)                                         \
    __builtin_amdgcn_global_load_lds(                                   \
        (const __attribute__((address_space(1))) uint32_t*)(gsrc),      \
        (__attribute__((address_space(3))) uint32_t*)(ldst), 16, 0, 0)

#define FMA4(A, X, mm) do { (A).x += (X).x*(mm); (A).y += (X).y*(mm); \
                            (A).z += (X).z*(mm); (A).w += (X).w*(mm); } while (0)

// ---------------------------------------------------------------------------
// Kernel A: collapse TT factor chains into small dense matrices. (unchanged)
// ---------------------------------------------------------------------------
__global__ __launch_bounds__(256) void precompute_kernel(
    const float* __restrict__ f0, const float* __restrict__ f1,
    const float* __restrict__ f2, const float* __restrict__ f3,
    const float* __restrict__ f4, const float* __restrict__ g0,
    const float* __restrict__ g1, const float* __restrict__ g2,
    float* __restrict__ ws)
{
    __shared__ float sA[8192];
    const int t = threadIdx.x;
    const int blk = blockIdx.x;
    if (blk < 8) {
        for (int i = t; i < 2048; i += 256) {
            int a01 = i >> 5, r2 = i & 31;
            int a0 = a01 >> 3, a1 = a01 & 7;
            float s = 0.f;
            #pragma unroll
            for (int r1 = 0; r1 < 32; ++r1)
                s += f0[a0*32 + r1] * f1[r1*256 + a1*32 + r2];
            sA[i] = s;
        }
        __syncthreads();
        for (int i = t; i < 2048; i += 256) {
            int a012 = blk*64 + (i >> 5), r3 = i & 31;
            int a01 = a012 >> 3, a2 = a012 & 7;
            float s = 0.f;
            #pragma unroll
            for (int r2 = 0; r2 < 32; ++r2)
                s += sA[a01*32 + r2] * f2[r2*256 + a2*32 + r3];
            ws[WS_M2 + a012*32 + r3] = s;
        }
    } else if (blk == 8) {
        for (int i = t; i < 2048; i += 256) {
            int a34 = i >> 5, s2 = i & 31;
            int a3 = a34 >> 3, a4 = a34 & 7;
            float s = 0.f;
            #pragma unroll
            for (int s1 = 0; s1 < 32; ++s1)
                s += f3[a3*32 + s1] * f4[s1*256 + a4*32 + s2];
            ws[WS_N2 + i] = s;
        }
    } else {
        const int j = blk - 9;   // 0..31, o-slice
        for (int i = t; i < 8192; i += 256) {
            int o01 = i >> 5, q = i & 31;
            int o0 = o01 >> 4, o1 = o01 & 15;
            float s = 0.f;
            #pragma unroll
            for (int p = 0; p < 32; ++p)
                s += g0[o0*32 + p] * g1[p*512 + o1*32 + q];
            sA[i] = s;
        }
        __syncthreads();
        for (int i = t; i < 4096; i += 256) {
            int o = j*128 + (i >> 5);
            int r = i & 31;
            int o01 = o >> 4, o2 = o & 15;
            float s = 0.f;
            #pragma unroll
            for (int q = 0; q < 32; ++q)
                s += sA[o01*32 + q] * g2[q*512 + o2*32 + r];
            ws[WS_WT + r*4096 + o] = s;
        }
    }
}

// ---------------------------------------------------------------------------
// Kernel B v7: 1024 blocks x 256 threads (4 waves), 1 batch/block, k-split.
//   Wave w: k in [128w, 128w+128), processed as 16 chunks of 8 k.
//   ALL VMEM is global_load_lds into WAVE-PRIVATE double buffers (x 2KB/chunk,
//   M2 1KB/chunk) with a COUNTED s_waitcnt vmcnt(3) per chunk -- no register
//   global-loads in the k-loop (nothing for the clobber to pin), no barriers.
//   Compute: thread (tm=lane&7, tr=lane>>3) owns 8m x 4r; per k: 2 b128 x +
//   1 b128 M2 (8 distinct addrs, 8-lane broadcast groups -> conflict-free)
//   + 32 FMAs into float4 accA[4]/accB[4] (constant-indexed).
//   Last chunk's free stage slot prefetches this wave's N2 quarter.
// LDS map, s[10240] = 40 KB -> 4 blocks/CU:
//   wave region R = s + w*2048:
//     k-loop: x dbuf R[0..1024) (2x512), M2 dbuf R[1024..1536) (2x256)
//     after:  partials [32 r][64 m] pitch 64, m-octet XOR-rotated:
//             addr = r*64 + ((om ^ (r&7))<<3) + (m&7)   (aliases dead dbufs)
//   N2 [8192..10240), staged during last chunk.
//   After reduce: T3t in w0 region [0..2048), T5 [2048..3072),
//                 spart [3072..3584)  (w1 region, dead).
// ---------------------------------------------------------------------------
__global__ __launch_bounds__(256, 4) void main_kernel(
    const float* __restrict__ x, const float* __restrict__ core,
    const float* __restrict__ ws, float* __restrict__ zout)
{
    __shared__ float s[10240];
    const int t = threadIdx.x;
    const int b = blockIdx.x;
    const int w    = __builtin_amdgcn_readfirstlane(t >> 6);  // wave 0..3
    const int lane = t & 63;
    const int tm = lane & 7;    // m-octet: m = tm*8 .. tm*8+7
    const int tr = lane >> 3;   // r-quad:  r = tr*4 .. tr*4+3

    float* __restrict__ R = s + w*2048;                        // wave region
    const float* __restrict__ xg = x + (size_t)b*32768 + w*8192;
    const float* __restrict__ mg = ws + WS_M2 + w*4096;

    // ---- prologue: stage chunk 0 (x: 512 floats, M2: 256 floats)
    GLOAD_LDS16(xg + lane*4,        R);
    GLOAD_LDS16(xg + 256 + lane*4,  R + 256);
    GLOAD_LDS16(mg + lane*4,        R + 1024);

    float4 accA[4], accB[4];
    #pragma unroll
    for (int rr = 0; rr < 4; ++rr) {
        accA[rr].x = accA[rr].y = accA[rr].z = accA[rr].w = 0.f;
        accB[rr].x = accB[rr].y = accB[rr].z = accB[rr].w = 0.f;
    }

    #pragma unroll 1
    for (int c = 0; c < 16; ++c) {
        if (c < 15) {   // stage chunk c+1 (3 loads), then wait for chunk c
            const float* sx = xg + (c+1)*512 + lane*4;
            float* dx = R + ((c+1)&1)*512;
            GLOAD_LDS16(sx,       dx);
            GLOAD_LDS16(sx + 256, dx + 256);
            GLOAD_LDS16(mg + (c+1)*256 + lane*4, R + 1024 + ((c+1)&1)*256);
            asm volatile("s_waitcnt vmcnt(3)" ::: "memory");
        } else {        // free slot: stage this wave's N2 quarter (2 loads)
            const float* sn = ws + WS_N2 + w*512 + lane*4;
            GLOAD_LDS16(sn,       s + 8192 + w*512);
            GLOAD_LDS16(sn + 256, s + 8192 + w*512 + 256);
            asm volatile("s_waitcnt vmcnt(2)" ::: "memory");
        }
        // compute chunk c: 8 k, all operands from wave-private LDS
        const float* __restrict__ xt = R + (c&1)*512 + tm*8;
        const float* __restrict__ mt = R + 1024 + (c&1)*256 + tr*4;
        #pragma unroll
        for (int kk = 0; kk < 8; ++kk) {
            float4 xlo = *(const float4*)(xt + kk*64);
            float4 xhi = *(const float4*)(xt + kk*64 + 4);
            float4 m4  = *(const float4*)(mt + kk*32);
            FMA4(accA[0], xlo, m4.x); FMA4(accB[0], xhi, m4.x);
            FMA4(accA[1], xlo, m4.y); FMA4(accB[1], xhi, m4.y);
            FMA4(accA[2], xlo, m4.z); FMA4(accB[2], xhi, m4.z);
            FMA4(accA[3], xlo, m4.w); FMA4(accB[3], xhi, m4.w);
        }
    }

    // ---- write partials into own dead region: [32 r][64 m] pitch 64,
    //      m-octet slot = (tm ^ (r&7))  (XOR rotation for phase-3 banks)
    #pragma unroll
    for (int rr = 0; rr < 4; ++rr) {
        const int r = tr*4 + rr;
        float* d = R + r*64 + ((tm ^ (r & 7)) << 3);
        d[0]=accA[rr].x; d[1]=accA[rr].y; d[2]=accA[rr].z; d[3]=accA[rr].w;
        d[4]=accB[rr].x; d[5]=accB[rr].y; d[6]=accB[rr].z; d[7]=accB[rr].w;
    }
    __syncthreads();   // also drains every wave's N2 staging (vmcnt(0))

    // ---- reduce over 4 k-quarters; final T3t lands in w0 region.
    //      thread: rr = t>>3 (row), mo = t&7 (logical m-octet); the stored
    //      slot for (rr, mo) is (mo ^ (rr&7)) -- thread-exclusive addresses.
    {
        const int rr = t >> 3;
        const int mo = t & 7;
        const int off = rr*64 + (((mo ^ (rr & 7))) << 3);
        float sm[8];
        #pragma unroll
        for (int i = 0; i < 8; ++i)
            sm[i] = s[off + i] + s[2048 + off + i]
                  + s[4096 + off + i] + s[6144 + off + i];
        #pragma unroll
        for (int i = 0; i < 8; ++i) s[off + i] = sm[i];
    }
    __syncthreads();

    // ---- phase 3: T5[r3,s2] = sum_m T3t[r3,m] * N2[m,s2] -> [2048..3072)
    //      T3t read applies the octet rotation: slot = ((m>>3) ^ (r3&7))
    {
        const int r3  = t >> 3;
        const int s2b = (t & 7) * 4;
        float a0=0.f, a1=0.f, a2=0.f, a3=0.f;
        #pragma unroll 8
        for (int m = 0; m < 64; ++m) {
            float av = s[r3*64 + (((m >> 3) ^ (r3 & 7)) << 3) + (m & 7)];
            const float* n = &s[8192 + m*32 + s2b];
            a0 += av*n[0]; a1 += av*n[1]; a2 += av*n[2]; a3 += av*n[3];
        }
        float* d = &s[2048 + r3*32 + s2b];
        d[0]=a0; d[1]=a1; d[2]=a2; d[3]=a3;
    }
    __syncthreads();

    // ---- phase 4: z[ro] = sum_k T5[k] * core[k,ro]
    {
        const int ro2 = t & 15;
        const int kc  = t >> 4;
        const float2* core2 = (const float2*)core;
        float s0 = 0.f, s1 = 0.f;
        const int k0 = kc * 64;
        for (int k = k0; k < k0 + 64; ++k) {
            float tv = s[2048 + k];
            float2 cv = core2[k*16 + ro2];
            s0 += tv*cv.x; s1 += tv*cv.y;
        }
        s[3072 + kc*32 + ro2*2 + 0] = s0;
        s[3072 + kc*32 + ro2*2 + 1] = s1;
    }
    __syncthreads();
    if (t < 32) {
        float acc = 0.f;
        #pragma unroll
        for (int kc = 0; kc < 16; ++kc) acc += s[3072 + kc*32 + t];
        zout[b*32 + t] = acc;
    }
}

// ---------------------------------------------------------------------------
// Kernel C: out[b,o] = sum_r z[b,r]*Wt[r,o] + bias[o]  (unchanged)
// ---------------------------------------------------------------------------
__global__ __launch_bounds__(256) void out_kernel(
    const float* __restrict__ ws, const float* __restrict__ bias,
    float* __restrict__ out)
{
    __shared__ float sW[8192];   // Wt tile [32][256]
    __shared__ float sZt[2176];  // z tile transposed [32 ro][68]
    __shared__ float sB[256];
    const int t  = threadIdx.x;
    const int bt = blockIdx.x;
    const int ot = blockIdx.y;

    {
        const float4* wt4 = (const float4*)(ws + WS_WT);
        float4* d = (float4*)sW;
        #pragma unroll
        for (int i = 0; i < 8; ++i) {
            int idx = i*256 + t;
            int ro = idx >> 6, oc = idx & 63;
            d[idx] = wt4[ro*1024 + ot*64 + oc];
        }
    }
    {
        const float4* z4 = (const float4*)(ws + WS_Z) + bt*512;
        #pragma unroll
        for (int i = 0; i < 2; ++i) {
            int idx = i*256 + t;
            int bl = idx >> 3, r4 = idx & 7;
            float4 v = z4[idx];
            sZt[(r4*4 + 0)*68 + bl] = v.x;
            sZt[(r4*4 + 1)*68 + bl] = v.y;
            sZt[(r4*4 + 2)*68 + bl] = v.z;
            sZt[(r4*4 + 3)*68 + bl] = v.w;
        }
    }
    if (t < 64) {
        const float4* b4 = (const float4*)bias + ot*64;
        ((float4*)sB)[t] = b4[t];
    }
    __syncthreads();

    const int oc = t & 63;
    const int bg = t >> 6;
    const float4* sW4 = (const float4*)sW;
    const float4 bv = ((const float4*)sB)[oc];
    float4* out4 = (float4*)out;

    for (int bi = 0; bi < 16; bi += 4) {
        const int bl = bg*16 + bi;
        float4 a0 = bv, a1 = bv, a2 = bv, a3 = bv;
        #pragma unroll
        for (int ro = 0; ro < 32; ++ro) {
            float4 w = sW4[ro*64 + oc];
            float4 z = *(const float4*)&sZt[ro*68 + bl];
            a0.x += z.x*w.x; a0.y += z.x*w.y; a0.z += z.x*w.z; a0.w += z.x*w.w;
            a1.x += z.y*w.x; a1.y += z.y*w.y; a1.z += z.y*w.z; a1.w += z.y*w.w;
            a2.x += z.z*w.x; a2.y += z.z*w.y; a2.z += z.z*w.z; a2.w += z.z*w.w;
            a3.x += z.w*w.x; a3.y += z.w*w.y; a3.z += z.w*w.z; a3.w += z.w*w.w;
        }
        const size_t obase = (size_t)(bt*64 + bl) * 1024 + ot*64 + oc;
        out4[obase + 0*1024] = a0;
        out4[obase + 1*1024] = a1;
        out4[obase + 2*1024] = a2;
        out4[obase + 3*1024] = a3;
    }
}

extern "C" void kernel_launch(void* const* d_in, const int* in_sizes, int n_in,
                              void* d_out, int out_size, void* d_ws, size_t ws_size,
                              hipStream_t stream)
{
    const float* x    = (const float*)d_in[0];
    const float* f0   = (const float*)d_in[1];
    const float* f1   = (const float*)d_in[2];
    const float* f2   = (const float*)d_in[3];
    const float* f3   = (const float*)d_in[4];
    const float* f4   = (const float*)d_in[5];
    const float* core = (const float*)d_in[6];
    const float* g0   = (const float*)d_in[7];
    const float* g1   = (const float*)d_in[8];
    const float* g2   = (const float*)d_in[9];
    const float* bias = (const float*)d_in[10];
    float* ws  = (float*)d_ws;
    float* out = (float*)d_out;

    precompute_kernel<<<41, 256, 0, stream>>>(f0, f1, f2, f3, f4, g0, g1, g2, ws);
    main_kernel<<<1024, 256, 0, stream>>>(x, core, ws, ws + WS_Z);
    out_kernel<<<dim3(16, 16), 256, 0, stream>>>(ws, bias, out);
}